// Round 1
// baseline (479.948 us; speedup 1.0000x reference)
//
#include <hip/hip_runtime.h>

// CostVolume1D: out[n,i,h,w] = (1/C) * sum_c f1[n,c,h,w] * f2pad[n,c,h,w+i-4]
// Shapes fixed by the reference: N=4, C=128, H=192, W=640, D=4 -> 9 shifts.
//
// Memory-bound (521 MB total traffic, ~83 us floor @6.3 TB/s). Strategy:
// read each input exactly once. One block per (n,h) row; f2 row staged in
// double-buffered LDS with +-4 zero halo (implements the zero padding);
// 9 fp32 accumulators per output element held in registers across the c-loop.

constexpr int DD = 4;
constexpr int NSHIFT = 2 * DD + 1;  // 9
constexpr int N_ = 4, C_ = 128, H_ = 192, W_ = 640;

__global__ __launch_bounds__(320)
void cost_volume_kernel(const float* __restrict__ f1,
                        const float* __restrict__ f2,
                        float* __restrict__ out)
{
    constexpr int HW = H_ * W_;
    const int t   = threadIdx.x;        // 0..319, owns w = 2t, 2t+1
    const int row = blockIdx.x;         // n*H + h
    const int n   = row / H_;
    const int h   = row - n * H_;

    const float* f1row = f1 + (size_t)n * C_ * HW + (size_t)h * W_;
    const float* f2row = f2 + (size_t)n * C_ * HW + (size_t)h * W_;

    // double-buffered f2 row with 4-float zero halo each side
    __shared__ float s[2][W_ + 2 * DD];   // 2 x 648 floats = 5184 B

    if (t < DD) {
        s[0][t] = 0.f;            s[1][t] = 0.f;
        s[0][DD + W_ + t] = 0.f;  s[1][DD + W_ + t] = 0.f;
    }

    const int w = 2 * t;
    float acc0[NSHIFT], acc1[NSHIFT];
#pragma unroll
    for (int i = 0; i < NSHIFT; ++i) { acc0[i] = 0.f; acc1[i] = 0.f; }

    // preload channel 0
    float2 a = *(const float2*)(f1row + w);
    {
        float2 b0 = *(const float2*)(f2row + w);
        *(float2*)&s[0][DD + w] = b0;
    }
    __syncthreads();

    int p = 0;
    for (int c = 0; c < C_ - 1; ++c) {
        // prefetch channel c+1 (coalesced 512B/wave)
        const float2 b_n = *(const float2*)(f2row + (size_t)(c + 1) * HW + w);
        const float2 a_n = *(const float2*)(f1row + (size_t)(c + 1) * HW + w);

        // compute on channel c from LDS buffer p
        float v[NSHIFT + 1];
        const float* sp = &s[p][w];     // sp[j] = f2[w + j - 4] (0 if OOB)
#pragma unroll
        for (int i = 0; i < 5; ++i)
            *(float2*)&v[2 * i] = *(const float2*)(sp + 2 * i);
#pragma unroll
        for (int i = 0; i < NSHIFT; ++i) {
            acc0[i] = fmaf(a.x, v[i],     acc0[i]);
            acc1[i] = fmaf(a.y, v[i + 1], acc1[i]);
        }

        // stage next channel into the other buffer
        *(float2*)&s[p ^ 1][DD + w] = b_n;
        __syncthreads();
        a = a_n;
        p ^= 1;
    }

    // last channel (no prefetch)
    {
        float v[NSHIFT + 1];
        const float* sp = &s[p][w];
#pragma unroll
        for (int i = 0; i < 5; ++i)
            *(float2*)&v[2 * i] = *(const float2*)(sp + 2 * i);
#pragma unroll
        for (int i = 0; i < NSHIFT; ++i) {
            acc0[i] = fmaf(a.x, v[i],     acc0[i]);
            acc1[i] = fmaf(a.y, v[i + 1], acc1[i]);
        }
    }

    constexpr float scale = 1.0f / (float)C_;
    float* orow = out + (size_t)n * NSHIFT * HW + (size_t)h * W_ + w;
#pragma unroll
    for (int i = 0; i < NSHIFT; ++i) {
        float2 o;
        o.x = acc0[i] * scale;
        o.y = acc1[i] * scale;
        *(float2*)(orow + (size_t)i * HW) = o;
    }
}

extern "C" void kernel_launch(void* const* d_in, const int* in_sizes, int n_in,
                              void* d_out, int out_size, void* d_ws, size_t ws_size,
                              hipStream_t stream) {
    const float* f1 = (const float*)d_in[0];
    const float* f2 = (const float*)d_in[1];
    float* out = (float*)d_out;
    dim3 grid(N_ * H_);   // 768 blocks = one per (n,h) row; exactly 3/CU
    dim3 block(320);      // 5 waves; each thread owns 2 w positions
    cost_volume_kernel<<<grid, block, 0, stream>>>(f1, f2, out);
}